// Round 12
// baseline (78.049 us; speedup 1.0000x reference)
//
#include <hip/hip_runtime.h>

#define HH 224
#define WW 224
#define NXCD 8
#define RB 8              // output rows per block
#define SROWS (RB + 14)   // staged rows: y0-7 .. y0+14 (22)
#define NT 448            // 7 waves
#define PPT 4             // RB*WW/NT = 4 pixels/thread
#define ROWF (WW * 3)     // 672 floats per staged LDS row (672%32==0)

// out[b,y,x,c] = sbp[b, Yi, Xi, c];  Yi=int((y+dy)%H), Xi=int((x+dx)%W)
// sbp border = 0; interior = 0.25*(tl+tr+bl+br) of channels 0..2.
__global__ __launch_bounds__(NT) void bilinear_lds_kernel(
    const float* __restrict__ x, float* __restrict__ out, int nwg) {
    __shared__ float rgb[SROWS][ROWF];  // 59136 B -> 2 blocks/CU

    // XCD-aware bijective swizzle (kept from round 4: 2.2x win).
    int p = blockIdx.x;
    int xcd = p % NXCD, idx = p / NXCD;
    int q = nwg / NXCD, r = nwg % NXCD;
    int lb = (xcd < r ? xcd * (q + 1) : r * (q + 1) + (xcd - r) * q) + idx;

    int img = lb / (HH / RB);  // 28 row-groups per image
    int rg  = lb % (HH / RB);
    int y0  = rg * RB;
    const float* base = x + (size_t)img * HH * WW * 5;

    int t = threadIdx.x;

    // (1) own-pixel dx/dy — issue early, consumed after the barrier.
    float dxv[PPT], dyv[PPT];
#pragma unroll
    for (int k = 0; k < PPT; ++k) {
        int pp = k * NT + t;  // 0..1791, lane-adjacent
        const float* pix = base + ((size_t)y0 * WW + pp) * 5;
        dxv[k] = pix[3];
        dyv[k] = pix[4];
    }

    // (2) stage 22 rows of RGB via DENSE float4 reads of the 5-ch stream.
    // Each row = 1120 floats = 280 aligned float4s; every fetched line is
    // looked up exactly once (vs ~5 scattered lookups/px in the direct form).
    for (int j = t; j < SROWS * 280; j += NT) {
        int row = j / 280;
        int c4  = j - row * 280;
        int g = y0 - 7 + row;
        g = (g + HH) % HH;  // wrap
        float4 v = *(const float4*)(base + (size_t)g * WW * 5 + c4 * 4);
        int f0 = c4 * 4;
        int px = f0 / 5;
        int ch = f0 - px * 5;
        float vv[4] = {v.x, v.y, v.z, v.w};
#pragma unroll
        for (int c = 0; c < 4; ++c) {
            if (ch < 3) rgb[row][px * 3 + ch] = vv[c];
            ++ch;
            if (ch == 5) { ch = 0; ++px; }
        }
    }
    __syncthreads();

    // (3) gather from LDS (global fallback only if |dy| ~> 6.99 — ~never).
#pragma unroll
    for (int k = 0; k < PPT; ++k) {
        int pp = k * NT + t;
        int prow = pp / WW;
        int pcol = pp - prow * WW;
        int py = y0 + prow;

        float rx = fmodf((float)pcol + dxv[k], (float)WW);
        if (rx < 0.f) rx += (float)WW;  // may round to exactly 224.0
        float ry = fmodf((float)py + dyv[k], (float)HH);
        if (ry < 0.f) ry += (float)HH;
        int xi = (int)rx; if (xi > WW - 1) xi = WW - 1;  // JAX clamps OOB
        int yi = (int)ry; if (yi > HH - 1) yi = HH - 1;

        float m = (xi >= 1 && xi <= WW - 2 && yi >= 1 && yi <= HH - 2) ? 0.25f : 0.f;
        int xc = xi < 1 ? 1 : (xi > WW - 2 ? WW - 2 : xi);
        int yc = yi < 1 ? 1 : (yi > HH - 2 ? HH - 2 : yi);

        // slot of yc in the staged window (mod-consistent with step 2).
        int s = yc - (y0 - 7);
        s = (s % HH + HH) % HH;

        float r0, g0, b0;
        if (s >= 1 && s <= SROWS - 2) {
            int cm = (xc - 1) * 3, cp = (xc + 1) * 3;
            r0 = rgb[s - 1][cm]     + rgb[s - 1][cp]     + rgb[s + 1][cm]     + rgb[s + 1][cp];
            g0 = rgb[s - 1][cm + 1] + rgb[s - 1][cp + 1] + rgb[s + 1][cm + 1] + rgb[s + 1][cp + 1];
            b0 = rgb[s - 1][cm + 2] + rgb[s - 1][cp + 2] + rgb[s + 1][cm + 2] + rgb[s + 1][cp + 2];
        } else {
            const float* p00 = base + ((size_t)(yc - 1) * WW + (xc - 1)) * 5;
            const float* p01 = base + ((size_t)(yc - 1) * WW + (xc + 1)) * 5;
            const float* p10 = base + ((size_t)(yc + 1) * WW + (xc - 1)) * 5;
            const float* p11 = base + ((size_t)(yc + 1) * WW + (xc + 1)) * 5;
            r0 = p00[0] + p01[0] + p10[0] + p11[0];
            g0 = p00[1] + p01[1] + p10[1] + p11[1];
            b0 = p00[2] + p01[2] + p10[2] + p11[2];
        }
        float* o = out + ((size_t)img * HH * WW + (size_t)y0 * WW + pp) * 3;
        o[0] = m * r0;
        o[1] = m * g0;
        o[2] = m * b0;
    }
}

extern "C" void kernel_launch(void* const* d_in, const int* in_sizes, int n_in,
                              void* d_out, int out_size, void* d_ws, size_t ws_size,
                              hipStream_t stream) {
    const float* x = (const float*)d_in[0];
    float* out = (float*)d_out;
    int B = in_sizes[0] / (HH * WW * 5);   // 128
    int blocks = B * (HH / RB);            // 3584
    bilinear_lds_kernel<<<blocks, NT, 0, stream>>>(x, out, blocks);
}

// Round 13
// 53.567 us; speedup vs baseline: 1.4570x; 1.4570x over previous
//
#include <hip/hip_runtime.h>

#define HH 224
#define WW 224
#define NXCD 8
#define RB 8              // output rows per block
#define SROWS (RB + 14)   // staged rows: y0-7 .. y0+14 (22)
#define NT 448            // 7 waves
#define PPT 4             // RB*WW/NT = 4 pixels/thread
#define ROWF (WW * 3)     // 672 floats per staged LDS row

// out[b,y,x,c] = sbp[b, Yi, Xi, c];  Yi=int((y+dy)%H), Xi=int((x+dx)%W)
// sbp border = 0; interior = 0.25*(tl+tr+bl+br) of channels 0..2.
__global__ __launch_bounds__(NT) void bilinear_lds_kernel(
    const float* __restrict__ x, float* __restrict__ out, int nwg) {
    __shared__ float rgb[SROWS][ROWF];  // 59136 B -> 2 blocks/CU

    // XCD-aware bijective swizzle (round 4: 2.2x win).
    int p = blockIdx.x;
    int xcd = p % NXCD, idx = p / NXCD;
    int q = nwg / NXCD, r = nwg % NXCD;
    int lb = (xcd < r ? xcd * (q + 1) : r * (q + 1) + (xcd - r) * q) + idx;

    int img = lb / (HH / RB);  // 28 row-groups per image
    int rg  = lb % (HH / RB);
    int y0  = rg * RB;
    const float* base = x + (size_t)img * HH * WW * 5;

    int t = threadIdx.x;

    // (1) own-pixel dx/dy — issued early, consumed after the barrier.
    float dxv[PPT], dyv[PPT];
#pragma unroll
    for (int k = 0; k < PPT; ++k) {
        int pp = k * NT + t;  // lane-adjacent
        const float* pix = base + ((size_t)y0 * WW + pp) * 5;
        dxv[k] = pix[3];
        dyv[k] = pix[4];
    }

    // (2) stage 22 rows of RGB, one PIXEL per iteration: 3 aligned scalar
    // loads + 3 ds_writes. Branch-free, no div-by-5 repack (round-12 lesson:
    // repack VALU + conflicts cost more than staged-line savings).
    for (int j = t; j < SROWS * WW; j += NT) {  // 4928/448 = 11 iters
        int row = j / WW;
        int px  = j - row * WW;
        int g = y0 - 7 + row;
        if (g < 0) g += HH;
        if (g >= HH) g -= HH;
        const float* src = base + ((size_t)g * WW + px) * 5;
        float* dst = &rgb[row][px * 3];
        dst[0] = src[0];
        dst[1] = src[1];
        dst[2] = src[2];
    }
    __syncthreads();

    // (3) gather from LDS (global fallback only if |dy| > ~6.99 — ~never).
#pragma unroll
    for (int k = 0; k < PPT; ++k) {
        int pp = k * NT + t;
        int prow = pp / WW;
        int pcol = pp - prow * WW;
        int py = y0 + prow;

        float rx = fmodf((float)pcol + dxv[k], (float)WW);
        if (rx < 0.f) rx += (float)WW;  // may round to exactly 224.0
        float ry = fmodf((float)py + dyv[k], (float)HH);
        if (ry < 0.f) ry += (float)HH;
        int xi = (int)rx; if (xi > WW - 1) xi = WW - 1;  // JAX clamps OOB
        int yi = (int)ry; if (yi > HH - 1) yi = HH - 1;

        float m = (xi >= 1 && xi <= WW - 2 && yi >= 1 && yi <= HH - 2) ? 0.25f : 0.f;
        int xc = xi < 1 ? 1 : (xi > WW - 2 ? WW - 2 : xi);
        int yc = yi < 1 ? 1 : (yi > HH - 2 ? HH - 2 : yi);

        // slot of yc in the staged window (mod-consistent with step 2).
        int s = yc - (y0 - 7);
        s = (s % HH + HH) % HH;

        float r0, g0, b0;
        if (s >= 1 && s <= SROWS - 2) {
            int cm = (xc - 1) * 3, cp = (xc + 1) * 3;
            r0 = rgb[s - 1][cm]     + rgb[s - 1][cp]     + rgb[s + 1][cm]     + rgb[s + 1][cp];
            g0 = rgb[s - 1][cm + 1] + rgb[s - 1][cp + 1] + rgb[s + 1][cm + 1] + rgb[s + 1][cp + 1];
            b0 = rgb[s - 1][cm + 2] + rgb[s - 1][cp + 2] + rgb[s + 1][cm + 2] + rgb[s + 1][cp + 2];
        } else {
            const float* p00 = base + ((size_t)(yc - 1) * WW + (xc - 1)) * 5;
            const float* p01 = base + ((size_t)(yc - 1) * WW + (xc + 1)) * 5;
            const float* p10 = base + ((size_t)(yc + 1) * WW + (xc - 1)) * 5;
            const float* p11 = base + ((size_t)(yc + 1) * WW + (xc + 1)) * 5;
            r0 = p00[0] + p01[0] + p10[0] + p11[0];
            g0 = p00[1] + p01[1] + p10[1] + p11[1];
            b0 = p00[2] + p01[2] + p10[2] + p11[2];
        }
        float* o = out + ((size_t)img * HH * WW + (size_t)y0 * WW + pp) * 3;
        o[0] = m * r0;
        o[1] = m * g0;
        o[2] = m * b0;
    }
}

extern "C" void kernel_launch(void* const* d_in, const int* in_sizes, int n_in,
                              void* d_out, int out_size, void* d_ws, size_t ws_size,
                              hipStream_t stream) {
    const float* x = (const float*)d_in[0];
    float* out = (float*)d_out;
    int B = in_sizes[0] / (HH * WW * 5);   // 128
    int blocks = B * (HH / RB);            // 3584
    bilinear_lds_kernel<<<blocks, NT, 0, stream>>>(x, out, blocks);
}

// Round 14
// 46.617 us; speedup vs baseline: 1.6743x; 1.1491x over previous
//
#include <hip/hip_runtime.h>

#define HH 224
#define WW 224
#define NXCD 8
#define RB 8              // output rows per block
#define SROWS (RB + 8)    // staged rows: y0-4 .. y0+11 (16)
#define NT 448            // 7 waves
#define PPT 4             // RB*WW/NT = 4 pixels/thread
#define ROWF (WW * 3)     // 672 floats per staged LDS row

// out[b,y,x,c] = sbp[b, Yi, Xi, c];  Yi=int((y+dy)%H), Xi=int((x+dx)%W)
// sbp border = 0; interior = 0.25*(tl+tr+bl+br) of channels 0..2.
__global__ __launch_bounds__(NT) void bilinear_lds_kernel(
    const float* __restrict__ x, float* __restrict__ out, int nwg) {
    __shared__ float rgb[SROWS][ROWF];  // 43008 B -> 3 blocks/CU

    // XCD-aware bijective swizzle (round 4: 2.2x win).
    int p = blockIdx.x;
    int xcd = p % NXCD, idx = p / NXCD;
    int q = nwg / NXCD, r = nwg % NXCD;
    int lb = (xcd < r ? xcd * (q + 1) : r * (q + 1) + (xcd - r) * q) + idx;

    int img = lb / (HH / RB);  // 28 row-groups per image
    int rg  = lb % (HH / RB);
    int y0  = rg * RB;
    const float* base = x + (size_t)img * HH * WW * 5;

    int t = threadIdx.x;

    // (1) own-pixel dx/dy as one float2 (offsets 12,16 within the 20B pixel).
    float dxv[PPT], dyv[PPT];
#pragma unroll
    for (int k = 0; k < PPT; ++k) {
        int pp = k * NT + t;  // lane-adjacent
        float2 d = *(const float2*)(base + ((size_t)y0 * WW + pp) * 5 + 3);
        dxv[k] = d.x;
        dyv[k] = d.y;
    }

    // (2) stage 16 rows of RGB: ONE float3 (dwordx3) load + one float3 LDS
    // write per staged pixel (round-13 lesson: 3 scalar loads tripled the
    // staging VMEM instruction count).
    for (int j = t; j < SROWS * WW; j += NT) {  // 3584/448 = 8 iters
        int row = j / WW;
        int px  = j - row * WW;
        int g = y0 - 4 + row;
        if (g < 0) g += HH;
        if (g >= HH) g -= HH;
        float3 v = *(const float3*)(base + ((size_t)g * WW + px) * 5);
        *(float3*)&rgb[row][px * 3] = v;
    }
    __syncthreads();

    // (3) gather from LDS (global fallback only when dy pushes outside the
    // 16-row window: P ~ 1e-3 on edge rows — rare, still correct).
#pragma unroll
    for (int k = 0; k < PPT; ++k) {
        int pp = k * NT + t;
        int prow = pp / WW;
        int pcol = pp - prow * WW;
        int py = y0 + prow;

        float rx = fmodf((float)pcol + dxv[k], (float)WW);
        if (rx < 0.f) rx += (float)WW;  // may round to exactly 224.0
        float ry = fmodf((float)py + dyv[k], (float)HH);
        if (ry < 0.f) ry += (float)HH;
        int xi = (int)rx; if (xi > WW - 1) xi = WW - 1;  // JAX clamps OOB
        int yi = (int)ry; if (yi > HH - 1) yi = HH - 1;

        float m = (xi >= 1 && xi <= WW - 2 && yi >= 1 && yi <= HH - 2) ? 0.25f : 0.f;
        int xc = xi < 1 ? 1 : (xi > WW - 2 ? WW - 2 : xi);
        int yc = yi < 1 ? 1 : (yi > HH - 2 ? HH - 2 : yi);

        // slot of yc in the staged window (mod-consistent with step 2).
        int s = yc - (y0 - 4);
        s = (s % HH + HH) % HH;

        float r0, g0, b0;
        if (s >= 1 && s <= SROWS - 2) {
            int cm = (xc - 1) * 3, cp = (xc + 1) * 3;
            float3 tl = *(const float3*)&rgb[s - 1][cm];
            float3 tr = *(const float3*)&rgb[s - 1][cp];
            float3 bl = *(const float3*)&rgb[s + 1][cm];
            float3 br = *(const float3*)&rgb[s + 1][cp];
            r0 = tl.x + tr.x + bl.x + br.x;
            g0 = tl.y + tr.y + bl.y + br.y;
            b0 = tl.z + tr.z + bl.z + br.z;
        } else {
            const float* p00 = base + ((size_t)(yc - 1) * WW + (xc - 1)) * 5;
            const float* p01 = base + ((size_t)(yc - 1) * WW + (xc + 1)) * 5;
            const float* p10 = base + ((size_t)(yc + 1) * WW + (xc - 1)) * 5;
            const float* p11 = base + ((size_t)(yc + 1) * WW + (xc + 1)) * 5;
            r0 = p00[0] + p01[0] + p10[0] + p11[0];
            g0 = p00[1] + p01[1] + p10[1] + p11[1];
            b0 = p00[2] + p01[2] + p10[2] + p11[2];
        }
        float* o = out + ((size_t)img * HH * WW + (size_t)y0 * WW + pp) * 3;
        *(float3*)o = make_float3(m * r0, m * g0, m * b0);
    }
}

extern "C" void kernel_launch(void* const* d_in, const int* in_sizes, int n_in,
                              void* d_out, int out_size, void* d_ws, size_t ws_size,
                              hipStream_t stream) {
    const float* x = (const float*)d_in[0];
    float* out = (float*)d_out;
    int B = in_sizes[0] / (HH * WW * 5);   // 128
    int blocks = B * (HH / RB);            // 3584
    bilinear_lds_kernel<<<blocks, NT, 0, stream>>>(x, out, blocks);
}

// Round 15
// 44.840 us; speedup vs baseline: 1.7406x; 1.0396x over previous
//
#include <hip/hip_runtime.h>

#define HH 224
#define WW 224
#define NXCD 8

// out[b,y,x,c] = sbp[b, Yi, Xi, c]
//   Yi = int((y + dy) mod H)  (jnp.remainder semantics), clamped to H-1
//   Xi = int((x + dx) mod W), clamped to W-1
//   sbp border = 0; interior = 0.25*(tl+tr+bl+br) of img (channels 0..2).
// Round-4 direct structure (46.2 us) + nontemporal stores + cheap exact mod.
__global__ __launch_bounds__(256) void bilinear_gather_kernel(
    const float* __restrict__ x, float* __restrict__ out, int nwg) {
    // XCD-aware bijective swizzle (round 3->4: 2.2x).
    int p = blockIdx.x;
    int xcd = p % NXCD, idx = p / NXCD;
    int q = nwg / NXCD, r = nwg % NXCD;
    int lb = (xcd < r ? xcd * (q + 1) : r * (q + 1) + (xcd - r) * q) + idx;

    int i = lb * 256 + threadIdx.x;  // total = 6422528 = 25088*256, no guard

    int px = i % WW;
    int t  = i / WW;
    int py = t % HH;
    int b  = t / HH;

    const float* pix = x + (size_t)i * 5;
    float2 d = *(const float2*)(pix + 3);
    float dx = d.x, dy = d.y;

    // Exact jnp.remainder for |d| < 224: v in (-224,448).
    //   v in [224,448): v-224 exact (Sterbenz). v in (-224,0): fmod(v)=v,
    //   then remainder adds 224 -- the SAME single fl(v+224) we compute here
    //   (may round to exactly 224.0 for tiny negatives -> clamp below).
    float rx = (float)px + dx;
    if (rx < 0.f) rx += (float)WW;
    else if (rx >= (float)WW) rx -= (float)WW;
    float ry = (float)py + dy;
    if (ry < 0.f) ry += (float)HH;
    else if (ry >= (float)HH) ry -= (float)HH;

    int xi = (int)rx; if (xi > WW - 1) xi = WW - 1;  // JAX clamps OOB gather
    int yi = (int)ry; if (yi > HH - 1) yi = HH - 1;

    float r0 = 0.f, g0 = 0.f, b0 = 0.f;
    if (xi >= 1 && xi <= WW - 2 && yi >= 1 && yi <= HH - 2) {
        const float* base = x + (size_t)b * HH * WW * 5;
        const float* p00 = base + ((size_t)(yi - 1) * WW + (xi - 1)) * 5;
        const float* p01 = base + ((size_t)(yi - 1) * WW + (xi + 1)) * 5;
        const float* p10 = base + ((size_t)(yi + 1) * WW + (xi - 1)) * 5;
        const float* p11 = base + ((size_t)(yi + 1) * WW + (xi + 1)) * 5;
        r0 = 0.25f * (p00[0] + p01[0] + p10[0] + p11[0]);
        g0 = 0.25f * (p00[1] + p01[1] + p10[1] + p11[1]);
        b0 = 0.25f * (p00[2] + p01[2] + p10[2] + p11[2]);
    }
    // Non-temporal: out is write-once, never re-read this replay. Keeps the
    // 75 MB write stream from evicting the 128 MB input out of L3.
    float* o = out + (size_t)i * 3;
    __builtin_nontemporal_store(r0, o);
    __builtin_nontemporal_store(g0, o + 1);
    __builtin_nontemporal_store(b0, o + 2);
}

extern "C" void kernel_launch(void* const* d_in, const int* in_sizes, int n_in,
                              void* d_out, int out_size, void* d_ws, size_t ws_size,
                              hipStream_t stream) {
    const float* x = (const float*)d_in[0];
    float* out = (float*)d_out;
    int total = in_sizes[0] / 5;        // B*H*W = 6422528
    int blocks = total / 256;           // 25088
    bilinear_gather_kernel<<<blocks, 256, 0, stream>>>(x, out, blocks);
}